// Round 1
// baseline (196.630 us; speedup 1.0000x reference)
//
#include <hip/hip_runtime.h>

// Problem constants
constexpr int NS    = 64;    // alphabet size
constexpr int SP    = 68;    // padded LDS row stride (floats); 4*68 % 32 = 16 -> 2-way aliasing only
constexpr int NM    = 8;     // models
constexpr int NB    = 1024;  // batch columns
constexpr int NEDGE = 62;
constexpr int NLEAF = 32;
constexpr int KT    = 12;    // Taylor degree (no scaling/squaring; ||tQ|| <~ 1.5)

// Workspace layout (float offsets)
constexpr size_t OFF_PT  = 0;                              // P transposed: PT[e][m][d][c] = P_em[c][d]
constexpr size_t SZ_PT   = (size_t)NEDGE * NM * NS * NS;   // 2,031,616
constexpr size_t OFF_Q   = OFF_PT + SZ_PT;                 // Q[m][i][j]
constexpr size_t SZ_Q    = (size_t)NM * NS * NS;
constexpr size_t OFF_QPT = OFF_Q + SZ_Q;                   // QpT[m][k-1][j][i] = (Q^k)[i][j]
constexpr size_t SZ_QPT  = (size_t)NM * KT * NS * NS;
constexpr size_t OFF_PI  = OFF_QPT + SZ_QPT;               // pi[m][s]
constexpr size_t SZ_PI   = (size_t)NM * NS;
constexpr size_t OFF_A   = OFF_PI + SZ_PI;                 // level ping buffer (16 nodes)
constexpr size_t SZ_A    = (size_t)16 * NM * NB * NS;      // 8,388,608
constexpr size_t OFF_B   = OFF_A + SZ_A;                   // level pong buffer (8 nodes)

__device__ __forceinline__ void acc4(float* a, const float4 pv,
                                     const float4 q0, const float4 q1,
                                     const float4 q2, const float4 q3) {
  a[0] = fmaf(pv.x, q0.x, fmaf(pv.y, q1.x, fmaf(pv.z, q2.x, fmaf(pv.w, q3.x, a[0]))));
  a[1] = fmaf(pv.x, q0.y, fmaf(pv.y, q1.y, fmaf(pv.z, q2.y, fmaf(pv.w, q3.y, a[1]))));
  a[2] = fmaf(pv.x, q0.z, fmaf(pv.y, q1.z, fmaf(pv.z, q2.z, fmaf(pv.w, q3.z, a[2]))));
  a[3] = fmaf(pv.x, q0.w, fmaf(pv.y, q1.w, fmaf(pv.z, q2.w, fmaf(pv.w, q3.w, a[3]))));
}

// ---------------- K1: pi + generator Q ----------------
__global__ __launch_bounds__(256) void k_setup(const float* __restrict__ R_inv,
                                               const float* __restrict__ pi_inv,
                                               float* __restrict__ ws) {
  const int m = blockIdx.x;
  const int tid = threadIdx.x;
  __shared__ float pis[NS];
  __shared__ float Qs[NS * SP];
  __shared__ float n2s;
  if (tid < 64) {
    float p = (tid < NS - 1) ? pi_inv[m * (NS - 1) + tid] : 0.f;
    float v = p * p;
    #pragma unroll
    for (int off = 32; off; off >>= 1) v += __shfl_down(v, off, 64);
    if (tid == 0) n2s = v;
  }
  __syncthreads();
  const float n2 = n2s;
  if (tid < 64) {
    const float den = n2 + 1.f;
    float x;
    if (tid < NS - 1) { float p = pi_inv[m * (NS - 1) + tid]; x = 2.f * p / den; }
    else              { x = (n2 - 1.f) / den; }
    const float pv = x * x;
    pis[tid] = pv;
    ws[OFF_PI + (size_t)m * NS + tid] = pv;
  }
  __syncthreads();
  // off-diagonal Q_ij = exp(R_k) * pi_j, symmetric exchangeabilities
  for (int idx = tid; idx < NS * NS; idx += 256) {
    const int i = idx >> 6, j = idx & 63;
    float q = 0.f;
    if (i != j) {
      const int a = min(i, j), b = max(i, j);
      const int k = a * (2 * NS - a - 1) / 2 + (b - a - 1);
      q = expf(R_inv[m * (NS * (NS - 1) / 2) + k]) * pis[j];
    }
    Qs[i * SP + j] = q;
  }
  __syncthreads();
  if (tid < 64) {
    float sum = 0.f;
    for (int j = 0; j < NS; ++j) sum += Qs[tid * SP + j];
    Qs[tid * SP + tid] = -sum;
  }
  __syncthreads();
  for (int idx = tid; idx < NS * NS; idx += 256)
    ws[OFF_Q + (size_t)m * NS * NS + idx] = Qs[(idx >> 6) * SP + (idx & 63)];
}

// 64x64 LDS matmul: C = A*B, 256 threads, 4x4 tiles, float4 chunked over k.
__device__ __forceinline__ void mm64(float* __restrict__ C, const float* __restrict__ A,
                                     const float* __restrict__ Bm) {
  const int tid = threadIdx.x;
  const int c0 = (tid & 15) * 4, r0 = (tid >> 4) * 4;
  float acc[4][4] = {};
  #pragma unroll 4
  for (int k = 0; k < NS; k += 4) {
    const float4 b0 = *(const float4*)&Bm[(k + 0) * SP + c0];
    const float4 b1 = *(const float4*)&Bm[(k + 1) * SP + c0];
    const float4 b2 = *(const float4*)&Bm[(k + 2) * SP + c0];
    const float4 b3 = *(const float4*)&Bm[(k + 3) * SP + c0];
    #pragma unroll
    for (int r = 0; r < 4; ++r) {
      const float4 av = *(const float4*)&A[(r0 + r) * SP + k];
      acc4(acc[r], av, b0, b1, b2, b3);
    }
  }
  __syncthreads();
  #pragma unroll
  for (int r = 0; r < 4; ++r)
    *(float4*)&C[(r0 + r) * SP + c0] =
        make_float4(acc[r][0], acc[r][1], acc[r][2], acc[r][3]);
  __syncthreads();
}

// ---------------- K2: matrix powers Q^k (k=1..KT), binary exponentiation ----------------
__global__ __launch_bounds__(256) void k_powers(float* __restrict__ ws) {
  const int m = blockIdx.x;
  const int k = blockIdx.y + 1;
  const int tid = threadIdx.x;
  __shared__ float buf[3][NS * SP];
  const float* Qg = ws + OFF_Q + (size_t)m * NS * NS;
  for (int idx = tid; idx < NS * NS; idx += 256)
    buf[0][(idx >> 6) * SP + (idx & 63)] = Qg[idx];
  __syncthreads();
  int cur = 0, acc = -1, f0 = 1, f1 = 2;
  int kk = k;
  while (true) {
    if (kk & 1) {
      if (acc < 0) {
        for (int idx = tid; idx < NS * SP; idx += 256) buf[f0][idx] = buf[cur][idx];
        __syncthreads();
        acc = f0; f0 = f1; f1 = -1;
      } else {
        mm64(buf[f0], buf[acc], buf[cur]);
        const int t = acc; acc = f0; f0 = t;
      }
    }
    kk >>= 1;
    if (!kk) break;
    mm64(buf[f0], buf[cur], buf[cur]);
    const int t = cur; cur = f0; f0 = t;
  }
  // store transposed: QpT[m][k-1][j][i] = Q^k[i][j]
  float* dst = ws + OFF_QPT + ((size_t)m * KT + (k - 1)) * NS * NS;
  for (int idx = tid; idx < NS * NS; idx += 256) {
    const int jj = idx >> 6, ii = idx & 63;
    dst[idx] = buf[acc][ii * SP + jj];
  }
}

// ---------------- K3: P_em^T = I + sum_k (t^k/k!) (Q^k)^T ----------------
__global__ __launch_bounds__(256) void k_combine(const float* __restrict__ lengths,
                                                 float* __restrict__ ws) {
  const int e = blockIdx.x, m = blockIdx.y, tid = threadIdx.x;
  const float t = lengths[e];
  const float* qp = ws + OFF_QPT + (size_t)m * KT * NS * NS;
  float* pt = ws + OFF_PT + ((size_t)e * NM + m) * NS * NS;
  float acc[16];
  #pragma unroll
  for (int r = 0; r < 16; ++r) {
    const int idx = tid + 256 * r;
    acc[r] = ((idx >> 6) == (idx & 63)) ? 1.f : 0.f;
  }
  float cf = 1.f;
  for (int k = 1; k <= KT; ++k) {
    cf *= t / (float)k;
    const float* qk = qp + (size_t)(k - 1) * NS * NS;
    #pragma unroll
    for (int r = 0; r < 16; ++r) acc[r] = fmaf(cf, qk[tid + 256 * r], acc[r]);
  }
  #pragma unroll
  for (int r = 0; r < 16; ++r) pt[tid + 256 * r] = acc[r];
}

// ---------------- K4: one pruning level; block = (sibling pair, model, 64-col tile) ----
// out[p][m][b][c] = (sum_d P_{e0}[c][d] prev[2p][b][d]) * (sum_d P_{e1}[c][d] prev[2p+1][b][d])
__global__ __launch_bounds__(256) void k_prune(const float* __restrict__ inbuf,
                                               float* __restrict__ outbuf,
                                               const float* __restrict__ ws,
                                               int edge_base, long long in_ns,
                                               long long in_ms, long long in_bs) {
  const int p = blockIdx.x, m = blockIdx.y, bt = blockIdx.z;
  const int tid = threadIdx.x;
  __shared__ float prev0[NS * SP], prev1[NS * SP], ptile[NS * SP];
  const float* in0 = inbuf + (long long)(2 * p) * in_ns + (long long)m * in_ms +
                     (long long)(bt * NS) * in_bs;
  const float* in1 = in0 + in_ns;
  for (int q = tid; q < 1024; q += 256) {
    const int bb = q >> 4, d4 = (q & 15) * 4;
    *(float4*)&prev0[bb * SP + d4] = *(const float4*)&in0[(long long)bb * in_bs + d4];
    *(float4*)&prev1[bb * SP + d4] = *(const float4*)&in1[(long long)bb * in_bs + d4];
  }
  const float* pt0 = ws + OFF_PT + ((size_t)(edge_base + 2 * p) * NM + m) * NS * NS;
  for (int q = tid; q < 1024; q += 256) {
    const int dd = q >> 4, c4 = (q & 15) * 4;
    *(float4*)&ptile[dd * SP + c4] = *(const float4*)&pt0[q * 4];
  }
  __syncthreads();
  const int c0 = (tid & 15) * 4, b0 = (tid >> 4) * 4;
  float a0[4][4] = {}, a1[4][4] = {};
  #pragma unroll 4
  for (int d = 0; d < NS; d += 4) {
    const float4 p0 = *(const float4*)&ptile[(d + 0) * SP + c0];
    const float4 p1 = *(const float4*)&ptile[(d + 1) * SP + c0];
    const float4 p2 = *(const float4*)&ptile[(d + 2) * SP + c0];
    const float4 p3 = *(const float4*)&ptile[(d + 3) * SP + c0];
    #pragma unroll
    for (int r = 0; r < 4; ++r) {
      const float4 pv = *(const float4*)&prev0[(b0 + r) * SP + d];
      acc4(a0[r], pv, p0, p1, p2, p3);
    }
  }
  __syncthreads();
  const float* pt1 = ws + OFF_PT + ((size_t)(edge_base + 2 * p + 1) * NM + m) * NS * NS;
  for (int q = tid; q < 1024; q += 256) {
    const int dd = q >> 4, c4 = (q & 15) * 4;
    *(float4*)&ptile[dd * SP + c4] = *(const float4*)&pt1[q * 4];
  }
  __syncthreads();
  #pragma unroll 4
  for (int d = 0; d < NS; d += 4) {
    const float4 p0 = *(const float4*)&ptile[(d + 0) * SP + c0];
    const float4 p1 = *(const float4*)&ptile[(d + 1) * SP + c0];
    const float4 p2 = *(const float4*)&ptile[(d + 2) * SP + c0];
    const float4 p3 = *(const float4*)&ptile[(d + 3) * SP + c0];
    #pragma unroll
    for (int r = 0; r < 4; ++r) {
      const float4 pv = *(const float4*)&prev1[(b0 + r) * SP + d];
      acc4(a1[r], pv, p0, p1, p2, p3);
    }
  }
  float* outp = outbuf + ((size_t)p * NM + m) * ((size_t)NB * NS) + (size_t)(bt * NS) * NS;
  #pragma unroll
  for (int r = 0; r < 4; ++r)
    *(float4*)&outp[(b0 + r) * NS + c0] =
        make_float4(a0[r][0] * a1[r][0], a0[r][1] * a1[r][1],
                    a0[r][2] * a1[r][2], a0[r][3] * a1[r][3]);
}

// ---------------- K5: out[b][m] = sum_s root[m][b][s] * pi[m][s] ----------------
__global__ __launch_bounds__(256) void k_final(float* __restrict__ out,
                                               const float* __restrict__ ws) {
  const int tid = threadIdx.x;
  const int lane = tid & 63, w = tid >> 6;
  const int gp = blockIdx.x * 4 + w;  // gp = b*8 + m
  const int b = gp >> 3, m = gp & 7;
  const float* root = ws + OFF_A;  // node 0 of ping buffer
  float v = root[(size_t)m * NB * NS + (size_t)b * NS + lane] *
            ws[OFF_PI + (size_t)m * NS + lane];
  #pragma unroll
  for (int off = 32; off; off >>= 1) v += __shfl_down(v, off, 64);
  if (lane == 0) out[gp] = v;
}

extern "C" void kernel_launch(void* const* d_in, const int* in_sizes, int n_in,
                              void* d_out, int out_size, void* d_ws, size_t ws_size,
                              hipStream_t stream) {
  const float* leaves  = (const float*)d_in[0];  // (B, 32, 64)
  const float* R_inv   = (const float*)d_in[1];  // (8, 2016)
  const float* pi_inv  = (const float*)d_in[2];  // (8, 63)
  const float* lengths = (const float*)d_in[3];  // (62,)
  float* out = (float*)d_out;                    // (B, 8)
  float* ws  = (float*)d_ws;

  hipLaunchKernelGGL(k_setup, dim3(NM), dim3(256), 0, stream, R_inv, pi_inv, ws);
  hipLaunchKernelGGL(k_powers, dim3(NM, KT), dim3(256), 0, stream, ws);
  hipLaunchKernelGGL(k_combine, dim3(NEDGE, NM), dim3(256), 0, stream, lengths, ws);

  float* bufA = ws + OFF_A;
  float* bufB = ws + OFF_B;
  const long long NSTRIDE = (long long)NM * NB * NS;  // node stride, internal buffers
  const long long MSTRIDE = (long long)NB * NS;
  // Level 0: input = leaves, strides (node=64, m=0, b=2048)
  hipLaunchKernelGGL(k_prune, dim3(16, NM, NB / 64), dim3(256), 0, stream,
                     leaves, bufA, ws, 0, (long long)NS, 0LL, (long long)(NLEAF * NS));
  hipLaunchKernelGGL(k_prune, dim3(8, NM, NB / 64), dim3(256), 0, stream,
                     bufA, bufB, ws, 32, NSTRIDE, MSTRIDE, (long long)NS);
  hipLaunchKernelGGL(k_prune, dim3(4, NM, NB / 64), dim3(256), 0, stream,
                     bufB, bufA, ws, 48, NSTRIDE, MSTRIDE, (long long)NS);
  hipLaunchKernelGGL(k_prune, dim3(2, NM, NB / 64), dim3(256), 0, stream,
                     bufA, bufB, ws, 56, NSTRIDE, MSTRIDE, (long long)NS);
  hipLaunchKernelGGL(k_prune, dim3(1, NM, NB / 64), dim3(256), 0, stream,
                     bufB, bufA, ws, 60, NSTRIDE, MSTRIDE, (long long)NS);

  hipLaunchKernelGGL(k_final, dim3(NB * NM / 4), dim3(256), 0, stream, out, ws);
}

// Round 2
// 166.163 us; speedup vs baseline: 1.1834x; 1.1834x over previous
//
#include <hip/hip_runtime.h>

typedef unsigned short u16;
typedef unsigned int u32;
typedef __attribute__((ext_vector_type(8))) __bf16 bf16x8;
typedef __attribute__((ext_vector_type(4))) float f32x4;

constexpr int NS = 64, NM = 8, NB = 1024, SP = 68;

// ---- workspace layout (float offsets), total 15,008,256 floats = 60.03 MB ----
constexpr size_t OFF_QP  = 0;         // fp32 powers Q^k: [m][k-1][64][64], k=1..12 (393216)
constexpr size_t OFF_PI  = 393216;    // pi fp32 [m][64] (512, padded)
constexpr size_t OFF_PBH = 393728;    // P hi bf16 [e][m][c][d] as u16 (1015808 floats)
constexpr size_t OFF_PBL = 1409536;   // P lo
constexpr size_t OFF_PGH = 2425344;   // ping hi: 16 nodes [n][m][b][d] u16 (4194304 floats)
constexpr size_t OFF_PGL = 6619648;   // ping lo
constexpr size_t OFF_POH = 10813952;  // pong hi: 8 nodes (2097152 floats)
constexpr size_t OFF_POL = 12911104;  // pong lo

union FR { uint4 u; bf16x8 v; };

// split x -> hi (RNE bf16) + lo (trunc bf16 of residual); hi+lo ~ 2^-15 accurate
__device__ __forceinline__ void split_bf16(float x, u16& h, u16& l) {
  u32 b = __float_as_uint(x);
  u32 hb = (b + 0x7fffu + ((b >> 16) & 1u)) & 0xffff0000u;
  h = (u16)(hb >> 16);
  float r = x - __uint_as_float(hb);
  l = (u16)(__float_as_uint(r) >> 16);
}

__device__ __forceinline__ void acc4(float* a, const float4 pv,
                                     const float4 q0, const float4 q1,
                                     const float4 q2, const float4 q3) {
  a[0] = fmaf(pv.x, q0.x, fmaf(pv.y, q1.x, fmaf(pv.z, q2.x, fmaf(pv.w, q3.x, a[0]))));
  a[1] = fmaf(pv.x, q0.y, fmaf(pv.y, q1.y, fmaf(pv.z, q2.y, fmaf(pv.w, q3.y, a[1]))));
  a[2] = fmaf(pv.x, q0.z, fmaf(pv.y, q1.z, fmaf(pv.z, q2.z, fmaf(pv.w, q3.z, a[2]))));
  a[3] = fmaf(pv.x, q0.w, fmaf(pv.y, q1.w, fmaf(pv.z, q2.w, fmaf(pv.w, q3.w, a[3]))));
}

// C(global, row-major 64x64) = A * B, both in LDS with SP padding
__device__ __forceinline__ void mm_tile_store(const float* __restrict__ A,
                                              const float* __restrict__ B,
                                              float* __restrict__ C, int tid) {
  const int c0 = (tid & 15) * 4, r0 = (tid >> 4) * 4;
  float acc[4][4] = {};
  #pragma unroll 4
  for (int k = 0; k < NS; k += 4) {
    const float4 b0 = *(const float4*)&B[(k + 0) * SP + c0];
    const float4 b1 = *(const float4*)&B[(k + 1) * SP + c0];
    const float4 b2 = *(const float4*)&B[(k + 2) * SP + c0];
    const float4 b3 = *(const float4*)&B[(k + 3) * SP + c0];
    #pragma unroll
    for (int r = 0; r < 4; ++r) {
      const float4 av = *(const float4*)&A[(r0 + r) * SP + k];
      acc4(acc[r], av, b0, b1, b2, b3);
    }
  }
  #pragma unroll
  for (int r = 0; r < 4; ++r)
    *(float4*)&C[(r0 + r) * 64 + c0] =
        make_float4(acc[r][0], acc[r][1], acc[r][2], acc[r][3]);
}

// ---------------- K1: pi + generator Q (-> QP slot k=1), fused Q^2 (-> slot k=2) ----
__global__ __launch_bounds__(256) void k_setup(const float* __restrict__ R_inv,
                                               const float* __restrict__ pi_inv,
                                               float* __restrict__ ws) {
  const int m = blockIdx.x;
  const int tid = threadIdx.x;
  __shared__ float pis[NS];
  __shared__ float Qs[NS * SP];
  __shared__ float n2s;
  if (tid < 64) {
    float p = (tid < NS - 1) ? pi_inv[m * (NS - 1) + tid] : 0.f;
    float v = p * p;
    #pragma unroll
    for (int off = 32; off; off >>= 1) v += __shfl_down(v, off, 64);
    if (tid == 0) n2s = v;
  }
  __syncthreads();
  const float n2 = n2s;
  if (tid < 64) {
    const float den = n2 + 1.f;
    float x;
    if (tid < NS - 1) { float p = pi_inv[m * (NS - 1) + tid]; x = 2.f * p / den; }
    else              { x = (n2 - 1.f) / den; }
    const float pv = x * x;
    pis[tid] = pv;
    ws[OFF_PI + (size_t)m * NS + tid] = pv;
  }
  __syncthreads();
  for (int idx = tid; idx < NS * NS; idx += 256) {
    const int i = idx >> 6, j = idx & 63;
    float q = 0.f;
    if (i != j) {
      const int a = min(i, j), b = max(i, j);
      const int k = a * (2 * NS - a - 1) / 2 + (b - a - 1);
      q = expf(R_inv[m * (NS * (NS - 1) / 2) + k]) * pis[j];
    }
    Qs[i * SP + j] = q;
  }
  __syncthreads();
  if (tid < 64) {
    float sum = 0.f;
    for (int j = 0; j < NS; ++j) sum += Qs[tid * SP + j];
    Qs[tid * SP + tid] = -sum;
  }
  __syncthreads();
  float* q1 = ws + OFF_QP + (size_t)m * 12 * 4096;
  for (int idx = tid; idx < NS * NS; idx += 256)
    q1[idx] = Qs[(idx >> 6) * SP + (idx & 63)];
  // fused: Q^2 -> slot k=2
  mm_tile_store(Qs, Qs, q1 + 4096, tid);
}

// ---------------- K2: squaring-ladder matmul, job table in kernel args ----------------
__global__ __launch_bounds__(256) void k_mm(float* __restrict__ ws, int4 t0, int4 t1,
                                            int4 t2, int4 t3) {
  const int m = blockIdx.x, job = blockIdx.y;
  const int4 T = (job == 0) ? t0 : (job == 1) ? t1 : (job == 2) ? t2 : t3;
  const float* A = ws + OFF_QP + ((size_t)m * 12 + (T.y - 1)) * 4096;
  const float* B = ws + OFF_QP + ((size_t)m * 12 + (T.z - 1)) * 4096;
  float* C = ws + OFF_QP + ((size_t)m * 12 + (T.x - 1)) * 4096;
  const int tid = threadIdx.x;
  __shared__ float As[NS * SP], Bs[NS * SP];
  for (int idx = tid; idx < 4096; idx += 256) {
    As[(idx >> 6) * SP + (idx & 63)] = A[idx];
    Bs[(idx >> 6) * SP + (idx & 63)] = B[idx];
  }
  __syncthreads();
  mm_tile_store(As, Bs, C, tid);
}

// ---------------- K3: P = I + sum_k (t^k/k!) Q^k, emitted as bf16 hi/lo row-major ----
__global__ __launch_bounds__(256) void k_combine(const float* __restrict__ lengths,
                                                 float* __restrict__ ws) {
  const int e = blockIdx.x, m = blockIdx.y, tid = threadIdx.x;
  const float t = lengths[e];
  const float* qp = ws + OFF_QP + (size_t)m * 12 * 4096;
  u16* ph = (u16*)(ws + OFF_PBH) + (((size_t)e * NM + m) << 12);
  u16* pl = (u16*)(ws + OFF_PBL) + (((size_t)e * NM + m) << 12);
  float acc[16];
  #pragma unroll
  for (int r = 0; r < 16; ++r) {
    const int idx = tid + 256 * r;
    acc[r] = ((idx >> 6) == (idx & 63)) ? 1.f : 0.f;
  }
  float cf = 1.f;
  for (int k = 1; k <= 12; ++k) {
    cf *= t / (float)k;
    const float* qk = qp + (size_t)(k - 1) * 4096;
    #pragma unroll
    for (int r = 0; r < 16; ++r) acc[r] = fmaf(cf, qk[tid + 256 * r], acc[r]);
  }
  #pragma unroll
  for (int r = 0; r < 16; ++r) {
    u16 h, l;
    split_bf16(acc[r], h, l);
    ph[tid + 256 * r] = h;
    pl[tid + 256 * r] = l;
  }
}

// ---------------- K4: one pruning level via split-bf16 MFMA ----------------
// Block = (sibling pair p, model m, 64-column batch tile). 4 waves in a 2x2
// (c-half, b-half) grid; each wave: 2x2 MFMA tiles of 16x16 per sibling.
// prev staged in LDS, XOR-swizzled 16B chunks: chunk (row, j) at row*128B +
// ((j+row)&7)*16B -> conflict-free ds_read_b128 fragment reads.
// P fragments loaded directly from global (hot in L2).
__global__ __launch_bounds__(256) void k_prune(
    const u16* __restrict__ inHi, const u16* __restrict__ inLo,
    const float* __restrict__ leaves, u16* __restrict__ outHi,
    u16* __restrict__ outLo, const u16* __restrict__ Phi,
    const u16* __restrict__ Plo, int edge_base, long long in_ns,
    long long in_ms, int lvl0) {
  const int p = blockIdx.x, m = blockIdx.y, bt64 = blockIdx.z;
  const int tid = threadIdx.x, lane = tid & 63, w = tid >> 6;
  __shared__ u32 smem[8192];  // 4 surfaces x 64 rows x 32 dwords (8KB each)

  if (lvl0) {
    // leaves fp32 [b][leaf][d]; split to hi/lo during staging
    #pragma unroll
    for (int s = 0; s < 2; ++s) {
      const float* g = leaves + (size_t)bt64 * 64 * 2048 + (size_t)(2 * p + s) * 64;
      #pragma unroll
      for (int it = 0; it < 2; ++it) {
        const int q = tid + it * 256;
        const int b = q >> 3, j = q & 7;
        const float4 v0 = *(const float4*)&g[(size_t)b * 2048 + j * 8];
        const float4 v1 = *(const float4*)&g[(size_t)b * 2048 + j * 8 + 4];
        u16 h[8], l[8];
        split_bf16(v0.x, h[0], l[0]); split_bf16(v0.y, h[1], l[1]);
        split_bf16(v0.z, h[2], l[2]); split_bf16(v0.w, h[3], l[3]);
        split_bf16(v1.x, h[4], l[4]); split_bf16(v1.y, h[5], l[5]);
        split_bf16(v1.z, h[6], l[6]); split_bf16(v1.w, h[7], l[7]);
        uint4 uh, ul;
        uh.x = h[0] | ((u32)h[1] << 16); uh.y = h[2] | ((u32)h[3] << 16);
        uh.z = h[4] | ((u32)h[5] << 16); uh.w = h[6] | ((u32)h[7] << 16);
        ul.x = l[0] | ((u32)l[1] << 16); ul.y = l[2] | ((u32)l[3] << 16);
        ul.z = l[4] | ((u32)l[5] << 16); ul.w = l[6] | ((u32)l[7] << 16);
        const int didx = (2 * s) * 2048 + b * 32 + (((j + b) & 7) << 2);
        *(uint4*)&smem[didx] = uh;
        *(uint4*)&smem[didx + 2048] = ul;
      }
    }
  } else {
    const long long base0 = (long long)(2 * p) * in_ns + (long long)m * in_ms +
                            (long long)bt64 * 4096;
    const u16* src[4] = {inHi + base0, inLo + base0, inHi + base0 + in_ns,
                         inLo + base0 + in_ns};
    #pragma unroll
    for (int s = 0; s < 4; ++s) {
      const uint4* g = (const uint4*)src[s];
      #pragma unroll
      for (int it = 0; it < 2; ++it) {
        const int q = tid + it * 256;
        const uint4 v = g[q];
        const int b = q >> 3, j = q & 7;
        *(uint4*)&smem[s * 2048 + b * 32 + (((j + b) & 7) << 2)] = v;
      }
    }
  }
  __syncthreads();

  const int kq = lane >> 4, ln = lane & 15;
  const int cq = (w & 1) * 32, bq = (w >> 1) * 32;
  const f32x4 z = {0.f, 0.f, 0.f, 0.f};
  f32x4 acc0[2][2] = {{z, z}, {z, z}}, acc1[2][2] = {{z, z}, {z, z}};

  #pragma unroll
  for (int s = 0; s < 2; ++s) {
    const size_t pbase = ((size_t)(edge_base + 2 * p + s) * NM + m) << 12;
    FR ah[2][2], al[2][2];
    #pragma unroll
    for (int ct = 0; ct < 2; ++ct)
      #pragma unroll
      for (int kh = 0; kh < 2; ++kh) {
        const size_t off = pbase + (size_t)(cq + ct * 16 + ln) * 64 + kh * 32 + kq * 8;
        ah[ct][kh].u = *(const uint4*)(Phi + off);
        al[ct][kh].u = *(const uint4*)(Plo + off);
      }
    #pragma unroll
    for (int bt = 0; bt < 2; ++bt) {
      FR bh[2], bl[2];
      #pragma unroll
      for (int kh = 0; kh < 2; ++kh) {
        const int b = bq + bt * 16 + ln;
        const int j = kh * 4 + kq;
        const int dh = (2 * s) * 2048 + b * 32 + (((j + b) & 7) << 2);
        bh[kh].u = *(const uint4*)&smem[dh];
        bl[kh].u = *(const uint4*)&smem[dh + 2048];
      }
      #pragma unroll
      for (int ct = 0; ct < 2; ++ct) {
        f32x4 a = (s ? acc1 : acc0)[ct][bt];
        #pragma unroll
        for (int kh = 0; kh < 2; ++kh) {
          a = __builtin_amdgcn_mfma_f32_16x16x32_bf16(ah[ct][kh].v, bh[kh].v, a, 0, 0, 0);
          a = __builtin_amdgcn_mfma_f32_16x16x32_bf16(ah[ct][kh].v, bl[kh].v, a, 0, 0, 0);
          a = __builtin_amdgcn_mfma_f32_16x16x32_bf16(al[ct][kh].v, bh[kh].v, a, 0, 0, 0);
        }
        (s ? acc1 : acc0)[ct][bt] = a;
      }
    }
  }

  // epilogue: sibling product, split to hi/lo, store row-major [b][c]
  const size_t outbase = ((size_t)p * NM + m) * ((size_t)NB * 64) + (size_t)bt64 * 4096;
  #pragma unroll
  for (int ct = 0; ct < 2; ++ct)
    #pragma unroll
    for (int bt = 0; bt < 2; ++bt) {
      const f32x4 x = acc0[ct][bt], y = acc1[ct][bt];
      float pr0 = x.x * y.x, pr1 = x.y * y.y, pr2 = x.z * y.z, pr3 = x.w * y.w;
      ushort4 h4, l4;
      split_bf16(pr0, h4.x, l4.x);
      split_bf16(pr1, h4.y, l4.y);
      split_bf16(pr2, h4.z, l4.z);
      split_bf16(pr3, h4.w, l4.w);
      const size_t o = outbase + (size_t)(bq + bt * 16 + ln) * 64 + cq + ct * 16 + kq * 4;
      *(ushort4*)(outHi + o) = h4;
      *(ushort4*)(outLo + o) = l4;
    }
}

// ---------------- K5: out[b][m] = sum_s (rootHi+rootLo)[m][b][s] * pi[m][s] --------
__global__ __launch_bounds__(256) void k_final(float* __restrict__ out,
                                               const float* __restrict__ ws) {
  const int tid = threadIdx.x, lane = tid & 63, w = tid >> 6;
  const int gp = blockIdx.x * 4 + w;  // gp = b*8 + m
  const int b = gp >> 3, m = gp & 7;
  const u16* rh = (const u16*)(ws + OFF_PGH);
  const u16* rl = (const u16*)(ws + OFF_PGL);
  const size_t o = (size_t)m * ((size_t)NB * 64) + (size_t)b * 64 + lane;
  float v = (__uint_as_float((u32)rh[o] << 16) + __uint_as_float((u32)rl[o] << 16)) *
            ws[OFF_PI + (size_t)m * 64 + lane];
  #pragma unroll
  for (int off = 32; off; off >>= 1) v += __shfl_down(v, off, 64);
  if (lane == 0) out[gp] = v;
}

extern "C" void kernel_launch(void* const* d_in, const int* in_sizes, int n_in,
                              void* d_out, int out_size, void* d_ws, size_t ws_size,
                              hipStream_t stream) {
  const float* leaves  = (const float*)d_in[0];  // (B, 32, 64)
  const float* R_inv   = (const float*)d_in[1];  // (8, 2016)
  const float* pi_inv  = (const float*)d_in[2];  // (8, 63)
  const float* lengths = (const float*)d_in[3];  // (62,)
  float* out = (float*)d_out;                    // (B, 8)
  float* ws  = (float*)d_ws;

  u16* PBH = (u16*)(ws + OFF_PBH);
  u16* PBL = (u16*)(ws + OFF_PBL);
  u16* PGH = (u16*)(ws + OFF_PGH);
  u16* PGL = (u16*)(ws + OFF_PGL);
  u16* POH = (u16*)(ws + OFF_POH);
  u16* POL = (u16*)(ws + OFF_POL);

  hipLaunchKernelGGL(k_setup, dim3(NM), dim3(256), 0, stream, R_inv, pi_inv, ws);
  // squaring ladder: Q^2 fused into k_setup; then {3,4}, {5..8}, {9..12}
  hipLaunchKernelGGL(k_mm, dim3(NM, 2), dim3(256), 0, stream, ws,
                     make_int4(3, 1, 2, 0), make_int4(4, 2, 2, 0),
                     make_int4(4, 2, 2, 0), make_int4(4, 2, 2, 0));
  hipLaunchKernelGGL(k_mm, dim3(NM, 4), dim3(256), 0, stream, ws,
                     make_int4(5, 1, 4, 0), make_int4(6, 2, 4, 0),
                     make_int4(7, 3, 4, 0), make_int4(8, 4, 4, 0));
  hipLaunchKernelGGL(k_mm, dim3(NM, 4), dim3(256), 0, stream, ws,
                     make_int4(9, 1, 8, 0), make_int4(10, 2, 8, 0),
                     make_int4(11, 3, 8, 0), make_int4(12, 4, 8, 0));
  hipLaunchKernelGGL(k_combine, dim3(62, NM), dim3(256), 0, stream, lengths, ws);

  const long long NSTR = (long long)NM * NB * 64;  // 524288
  const long long MSTR = (long long)NB * 64;       // 65536
  hipLaunchKernelGGL(k_prune, dim3(16, NM, 16), dim3(256), 0, stream,
                     (const u16*)nullptr, (const u16*)nullptr, leaves,
                     PGH, PGL, PBH, PBL, 0, 0LL, 0LL, 1);
  hipLaunchKernelGGL(k_prune, dim3(8, NM, 16), dim3(256), 0, stream,
                     PGH, PGL, (const float*)nullptr, POH, POL, PBH, PBL,
                     32, NSTR, MSTR, 0);
  hipLaunchKernelGGL(k_prune, dim3(4, NM, 16), dim3(256), 0, stream,
                     POH, POL, (const float*)nullptr, PGH, PGL, PBH, PBL,
                     48, NSTR, MSTR, 0);
  hipLaunchKernelGGL(k_prune, dim3(2, NM, 16), dim3(256), 0, stream,
                     PGH, PGL, (const float*)nullptr, POH, POL, PBH, PBL,
                     56, NSTR, MSTR, 0);
  hipLaunchKernelGGL(k_prune, dim3(1, NM, 16), dim3(256), 0, stream,
                     POH, POL, (const float*)nullptr, PGH, PGL, PBH, PBL,
                     60, NSTR, MSTR, 0);

  hipLaunchKernelGGL(k_final, dim3(NB * NM / 4), dim3(256), 0, stream, out, ws);
}

// Round 3
// 139.613 us; speedup vs baseline: 1.4084x; 1.1902x over previous
//
#include <hip/hip_runtime.h>

typedef unsigned short u16;
typedef unsigned int u32;
typedef __attribute__((ext_vector_type(8))) __bf16 bf16x8;
typedef __attribute__((ext_vector_type(4))) float f32x4;

constexpr int NS = 64, NM = 8, NB = 1024, SP = 68;

// ---- workspace layout (float offsets), total ~9.7 MB ----
constexpr size_t OFF_QP  = 0;                       // fp32 Q^k: [m][k-1][64*64], k=1..12
constexpr size_t OFF_PI  = 393216;                  // pi fp32 [m][64]
constexpr size_t OFF_PBH = 393728;                  // P hi bf16 [e][m][c][d] as u16
constexpr size_t OFF_PBL = OFF_PBH + 1015808;       // P lo

union FR { uint4 u; bf16x8 v; };
struct Frag { FR h, l; };

// split x -> hi (RNE bf16) + lo (trunc bf16 of residual)
__device__ __forceinline__ void split_bf16(float x, u16& h, u16& l) {
  u32 b = __float_as_uint(x);
  u32 hb = (b + 0x7fffu + ((b >> 16) & 1u)) & 0xffff0000u;
  h = (u16)(hb >> 16);
  float r = x - __uint_as_float(hb);
  l = (u16)(__float_as_uint(r) >> 16);
}

__device__ __forceinline__ void mfma3(f32x4& a, const Frag& A, const FR& Bh,
                                      const FR& Bl) {
  a = __builtin_amdgcn_mfma_f32_16x16x32_bf16(A.h.v, Bh.v, a, 0, 0, 0);
  a = __builtin_amdgcn_mfma_f32_16x16x32_bf16(A.h.v, Bl.v, a, 0, 0, 0);
  a = __builtin_amdgcn_mfma_f32_16x16x32_bf16(A.l.v, Bh.v, a, 0, 0, 0);
}

__device__ __forceinline__ void acc4(float* a, const float4 pv,
                                     const float4 q0, const float4 q1,
                                     const float4 q2, const float4 q3) {
  a[0] = fmaf(pv.x, q0.x, fmaf(pv.y, q1.x, fmaf(pv.z, q2.x, fmaf(pv.w, q3.x, a[0]))));
  a[1] = fmaf(pv.x, q0.y, fmaf(pv.y, q1.y, fmaf(pv.z, q2.y, fmaf(pv.w, q3.y, a[1]))));
  a[2] = fmaf(pv.x, q0.z, fmaf(pv.y, q1.z, fmaf(pv.z, q2.z, fmaf(pv.w, q3.z, a[2]))));
  a[3] = fmaf(pv.x, q0.w, fmaf(pv.y, q1.w, fmaf(pv.z, q2.w, fmaf(pv.w, q3.w, a[3]))));
}

// C(global, row-major 64x64) = A * B, both in LDS with SP padding
__device__ __forceinline__ void mm_tile_store(const float* __restrict__ A,
                                              const float* __restrict__ B,
                                              float* __restrict__ C, int tid) {
  const int c0 = (tid & 15) * 4, r0 = (tid >> 4) * 4;
  float acc[4][4] = {};
  #pragma unroll 4
  for (int k = 0; k < NS; k += 4) {
    const float4 b0 = *(const float4*)&B[(k + 0) * SP + c0];
    const float4 b1 = *(const float4*)&B[(k + 1) * SP + c0];
    const float4 b2 = *(const float4*)&B[(k + 2) * SP + c0];
    const float4 b3 = *(const float4*)&B[(k + 3) * SP + c0];
    #pragma unroll
    for (int r = 0; r < 4; ++r) {
      const float4 av = *(const float4*)&A[(r0 + r) * SP + k];
      acc4(acc[r], av, b0, b1, b2, b3);
    }
  }
  #pragma unroll
  for (int r = 0; r < 4; ++r)
    *(float4*)&C[(r0 + r) * 64 + c0] =
        make_float4(acc[r][0], acc[r][1], acc[r][2], acc[r][3]);
}

// ---------------- K1: pi + generator Q (-> QP k=1), fused Q^2 (-> k=2) ----
__global__ __launch_bounds__(256) void k_setup(const float* __restrict__ R_inv,
                                               const float* __restrict__ pi_inv,
                                               float* __restrict__ ws) {
  const int m = blockIdx.x;
  const int tid = threadIdx.x;
  __shared__ float pis[NS];
  __shared__ float Qs[NS * SP];
  __shared__ float n2s;
  if (tid < 64) {
    float p = (tid < NS - 1) ? pi_inv[m * (NS - 1) + tid] : 0.f;
    float v = p * p;
    #pragma unroll
    for (int off = 32; off; off >>= 1) v += __shfl_down(v, off, 64);
    if (tid == 0) n2s = v;
  }
  __syncthreads();
  const float n2 = n2s;
  if (tid < 64) {
    const float den = n2 + 1.f;
    float x;
    if (tid < NS - 1) { float p = pi_inv[m * (NS - 1) + tid]; x = 2.f * p / den; }
    else              { x = (n2 - 1.f) / den; }
    const float pv = x * x;
    pis[tid] = pv;
    ws[OFF_PI + (size_t)m * NS + tid] = pv;
  }
  __syncthreads();
  for (int idx = tid; idx < NS * NS; idx += 256) {
    const int i = idx >> 6, j = idx & 63;
    float q = 0.f;
    if (i != j) {
      const int a = min(i, j), b = max(i, j);
      const int k = a * (2 * NS - a - 1) / 2 + (b - a - 1);
      q = expf(R_inv[m * (NS * (NS - 1) / 2) + k]) * pis[j];
    }
    Qs[i * SP + j] = q;
  }
  __syncthreads();
  if (tid < 64) {
    float sum = 0.f;
    for (int j = 0; j < NS; ++j) sum += Qs[tid * SP + j];
    Qs[tid * SP + tid] = -sum;
  }
  __syncthreads();
  float* q1 = ws + OFF_QP + (size_t)m * 12 * 4096;
  for (int idx = tid; idx < NS * NS; idx += 256)
    q1[idx] = Qs[(idx >> 6) * SP + (idx & 63)];
  mm_tile_store(Qs, Qs, q1 + 4096, tid);
}

// ---------------- K2: squaring-ladder matmul ----------------
__global__ __launch_bounds__(256) void k_mm(float* __restrict__ ws, int4 t0, int4 t1,
                                            int4 t2, int4 t3) {
  const int m = blockIdx.x, job = blockIdx.y;
  const int4 T = (job == 0) ? t0 : (job == 1) ? t1 : (job == 2) ? t2 : t3;
  const float* A = ws + OFF_QP + ((size_t)m * 12 + (T.y - 1)) * 4096;
  const float* B = ws + OFF_QP + ((size_t)m * 12 + (T.z - 1)) * 4096;
  float* C = ws + OFF_QP + ((size_t)m * 12 + (T.x - 1)) * 4096;
  const int tid = threadIdx.x;
  __shared__ float As[NS * SP], Bs[NS * SP];
  for (int idx = tid; idx < 4096; idx += 256) {
    As[(idx >> 6) * SP + (idx & 63)] = A[idx];
    Bs[(idx >> 6) * SP + (idx & 63)] = B[idx];
  }
  __syncthreads();
  mm_tile_store(As, Bs, C, tid);
}

// ---------------- K3: P = I + sum_k (t^k/k!) Q^k -> bf16 hi/lo row-major ----
__global__ __launch_bounds__(256) void k_combine(const float* __restrict__ lengths,
                                                 float* __restrict__ ws) {
  const int e = blockIdx.x, m = blockIdx.y, tid = threadIdx.x;
  const float t = lengths[e];
  const float* qp = ws + OFF_QP + (size_t)m * 12 * 4096;
  u16* ph = (u16*)(ws + OFF_PBH) + (((size_t)e * NM + m) << 12);
  u16* pl = (u16*)(ws + OFF_PBL) + (((size_t)e * NM + m) << 12);
  float acc[16];
  #pragma unroll
  for (int r = 0; r < 16; ++r) {
    const int idx = tid + 256 * r;
    acc[r] = ((idx >> 6) == (idx & 63)) ? 1.f : 0.f;
  }
  float cf = 1.f;
  for (int k = 1; k <= 12; ++k) {
    cf *= t / (float)k;
    const float* qk = qp + (size_t)(k - 1) * 4096;
    #pragma unroll
    for (int r = 0; r < 16; ++r) acc[r] = fmaf(cf, qk[tid + 256 * r], acc[r]);
  }
  #pragma unroll
  for (int r = 0; r < 16; ++r) {
    u16 h, l;
    split_bf16(acc[r], h, l);
    ph[tid + 256 * r] = h;
    pl[tid + 256 * r] = l;
  }
}

// ---------------- K4: fully-fused tree pruning + final dot ----------------
// Grid: 256 blocks = (m = blockIdx.x&7 for XCD L2 affinity) x (btile of 32 cols).
// 8 waves; all 5 levels in LDS. Node slot s: 32 rows x 32 dwords hi (+1024 lo);
// row b chunk j (16B, d=8j..8j+7) XOR-swizzled to position ((j+b)&7).
// In-place slot reuse: pair p's output overwrites sibling-0's slot; safe because
// only the owning wave reads those slots (DS same-wave ordering) + level barriers.
__global__ __launch_bounds__(512) void k_tree(
    const float* __restrict__ leaves, const u16* __restrict__ Phi,
    const u16* __restrict__ Plo, const float* __restrict__ ws,
    float* __restrict__ out) {
  const int m = blockIdx.x & 7, btile = blockIdx.x >> 3;
  const int tid = threadIdx.x, lane = tid & 63, w = tid >> 6;
  const int ln = lane & 15, kq = lane >> 4;
  __shared__ u32 nodes[16 * 2048];  // 128 KB
  __shared__ float part[2][4][16];

  const f32x4 z = {0.f, 0.f, 0.f, 0.f};

  auto do_pair = [&](int p, int eb, int in_shift, int out_slot, int bt0, int bt1,
                     int ct0, int ct1, bool lvl0, f32x4 (*rootout)[2]) {
    FR Bh[2][2][2], Bl[2][2][2];  // [sib][bt][kh]
    #pragma unroll
    for (int s = 0; s < 2; ++s)
      #pragma unroll
      for (int bt = 0; bt < 2; ++bt) {
        if (bt < bt0 || bt > bt1) continue;
        #pragma unroll
        for (int kh = 0; kh < 2; ++kh) {
          if (lvl0) {
            const int b = btile * 32 + bt * 16 + ln;
            const float* g = leaves + (size_t)b * 2048 + (eb + 2 * p + s) * 64 +
                             kh * 32 + kq * 8;
            const float4 v0 = *(const float4*)g;
            const float4 v1 = *(const float4*)(g + 4);
            u16 h[8], l[8];
            split_bf16(v0.x, h[0], l[0]); split_bf16(v0.y, h[1], l[1]);
            split_bf16(v0.z, h[2], l[2]); split_bf16(v0.w, h[3], l[3]);
            split_bf16(v1.x, h[4], l[4]); split_bf16(v1.y, h[5], l[5]);
            split_bf16(v1.z, h[6], l[6]); split_bf16(v1.w, h[7], l[7]);
            uint4 uh, ul;
            uh.x = h[0] | ((u32)h[1] << 16); uh.y = h[2] | ((u32)h[3] << 16);
            uh.z = h[4] | ((u32)h[5] << 16); uh.w = h[6] | ((u32)h[7] << 16);
            ul.x = l[0] | ((u32)l[1] << 16); ul.y = l[2] | ((u32)l[3] << 16);
            ul.z = l[4] | ((u32)l[5] << 16); ul.w = l[6] | ((u32)l[7] << 16);
            Bh[s][bt][kh].u = uh;
            Bl[s][bt][kh].u = ul;
          } else {
            const int slot = (2 * p + s) << in_shift;
            const int b = bt * 16 + ln;
            const int base = slot * 2048 + b * 32 + (((kh * 4 + kq) + b) & 7) * 4;
            Bh[s][bt][kh].u = *(const uint4*)&nodes[base];
            Bl[s][bt][kh].u = *(const uint4*)&nodes[base + 1024];
          }
        }
      }
    // sibling-0 accumulators for all (ct,bt) in range
    f32x4 acc0[4][2];
    #pragma unroll
    for (int ct = 0; ct < 4; ++ct)
      #pragma unroll
      for (int bt = 0; bt < 2; ++bt) acc0[ct][bt] = z;
    const size_t pb0 = ((size_t)(eb + 2 * p) * NM + m) << 12;
    const size_t pb1 = ((size_t)(eb + 2 * p + 1) * NM + m) << 12;
    #pragma unroll
    for (int ct = 0; ct < 4; ++ct) {
      if (ct < ct0 || ct > ct1) continue;
      Frag A[2];
      #pragma unroll
      for (int kh = 0; kh < 2; ++kh) {
        const size_t off = pb0 + (size_t)(ct * 16 + ln) * 64 + kh * 32 + kq * 8;
        A[kh].h.u = *(const uint4*)(Phi + off);
        A[kh].l.u = *(const uint4*)(Plo + off);
      }
      #pragma unroll
      for (int bt = 0; bt < 2; ++bt) {
        if (bt < bt0 || bt > bt1) continue;
        #pragma unroll
        for (int kh = 0; kh < 2; ++kh)
          mfma3(acc0[ct][bt], A[kh], Bh[0][bt][kh], Bl[0][bt][kh]);
      }
    }
    // sibling-1 + elementwise product + output
    #pragma unroll
    for (int ct = 0; ct < 4; ++ct) {
      if (ct < ct0 || ct > ct1) continue;
      Frag A[2];
      #pragma unroll
      for (int kh = 0; kh < 2; ++kh) {
        const size_t off = pb1 + (size_t)(ct * 16 + ln) * 64 + kh * 32 + kq * 8;
        A[kh].h.u = *(const uint4*)(Phi + off);
        A[kh].l.u = *(const uint4*)(Plo + off);
      }
      #pragma unroll
      for (int bt = 0; bt < 2; ++bt) {
        if (bt < bt0 || bt > bt1) continue;
        f32x4 a1 = z;
        #pragma unroll
        for (int kh = 0; kh < 2; ++kh)
          mfma3(a1, A[kh], Bh[1][bt][kh], Bl[1][bt][kh]);
        f32x4 pr;
        pr.x = acc0[ct][bt].x * a1.x;
        pr.y = acc0[ct][bt].y * a1.y;
        pr.z = acc0[ct][bt].z * a1.z;
        pr.w = acc0[ct][bt].w * a1.w;
        if (rootout) {
          rootout[ct][bt] = pr;
        } else {
          u16 h[4], l[4];
          split_bf16(pr.x, h[0], l[0]); split_bf16(pr.y, h[1], l[1]);
          split_bf16(pr.z, h[2], l[2]); split_bf16(pr.w, h[3], l[3]);
          const int b = bt * 16 + ln;
          const int jc = ct * 2 + (kq >> 1);
          const int base =
              out_slot * 2048 + b * 32 + ((jc + b) & 7) * 4 + (kq & 1) * 2;
          uint2 wh, wl;
          wh.x = h[0] | ((u32)h[1] << 16); wh.y = h[2] | ((u32)h[3] << 16);
          wl.x = l[0] | ((u32)l[1] << 16); wl.y = l[2] | ((u32)l[3] << 16);
          *(uint2*)&nodes[base] = wh;
          *(uint2*)&nodes[base + 1024] = wl;
        }
      }
    }
  };

  // L0: 16 pairs, leaves -> slots 0..15
  do_pair(w, 0, 0, w, 0, 1, 0, 3, true, nullptr);
  do_pair(w + 8, 0, 0, w + 8, 0, 1, 0, 3, true, nullptr);
  __syncthreads();
  // L1: 8 pairs, slots (2p,2p+1) -> slot 2p
  do_pair(w, 32, 0, 2 * w, 0, 1, 0, 3, false, nullptr);
  __syncthreads();
  // L2: 4 pairs x 2 bt-waves, slots (4p,4p+2) -> 4p
  do_pair(w >> 1, 48, 1, 4 * (w >> 1), w & 1, w & 1, 0, 3, false, nullptr);
  __syncthreads();
  // L3: 2 pairs x 2 bt-waves (waves 0-3), slots (8p,8p+4) -> 8p
  if (w < 4)
    do_pair(w >> 1, 56, 2, 8 * (w >> 1), w & 1, w & 1, 0, 3, false, nullptr);
  __syncthreads();
  // L4 root: slots (0,8); one 16x16 tile per wave, no write
  f32x4 prod[4][2];
  do_pair(0, 60, 3, 0, w >> 2, w >> 2, w & 3, w & 3, false, prod);
  {
    const int ct = w & 3, bt = w >> 2;
    const float4 piv =
        *(const float4*)&ws[OFF_PI + (size_t)m * 64 + ct * 16 + kq * 4];
    const f32x4 pr = prod[ct][bt];
    float v = pr.x * piv.x + pr.y * piv.y + pr.z * piv.z + pr.w * piv.w;
    v += __shfl_xor(v, 16, 64);
    v += __shfl_xor(v, 32, 64);
    if (lane < 16) part[bt][ct][lane] = v;
  }
  __syncthreads();
  if (tid < 32) {
    const int bt = tid >> 4, bl = tid & 15;
    const float s =
        part[bt][0][bl] + part[bt][1][bl] + part[bt][2][bl] + part[bt][3][bl];
    out[(size_t)(btile * 32 + tid) * 8 + m] = s;
  }
}

extern "C" void kernel_launch(void* const* d_in, const int* in_sizes, int n_in,
                              void* d_out, int out_size, void* d_ws, size_t ws_size,
                              hipStream_t stream) {
  const float* leaves  = (const float*)d_in[0];  // (B, 32, 64)
  const float* R_inv   = (const float*)d_in[1];  // (8, 2016)
  const float* pi_inv  = (const float*)d_in[2];  // (8, 63)
  const float* lengths = (const float*)d_in[3];  // (62,)
  float* out = (float*)d_out;                    // (B, 8)
  float* ws  = (float*)d_ws;

  u16* PBH = (u16*)(ws + OFF_PBH);
  u16* PBL = (u16*)(ws + OFF_PBL);

  hipLaunchKernelGGL(k_setup, dim3(NM), dim3(256), 0, stream, R_inv, pi_inv, ws);
  hipLaunchKernelGGL(k_mm, dim3(NM, 2), dim3(256), 0, stream, ws,
                     make_int4(3, 1, 2, 0), make_int4(4, 2, 2, 0),
                     make_int4(4, 2, 2, 0), make_int4(4, 2, 2, 0));
  hipLaunchKernelGGL(k_mm, dim3(NM, 4), dim3(256), 0, stream, ws,
                     make_int4(5, 1, 4, 0), make_int4(6, 2, 4, 0),
                     make_int4(7, 3, 4, 0), make_int4(8, 4, 4, 0));
  hipLaunchKernelGGL(k_mm, dim3(NM, 4), dim3(256), 0, stream, ws,
                     make_int4(9, 1, 8, 0), make_int4(10, 2, 8, 0),
                     make_int4(11, 3, 8, 0), make_int4(12, 4, 8, 0));
  hipLaunchKernelGGL(k_combine, dim3(62, NM), dim3(256), 0, stream, lengths, ws);
  hipLaunchKernelGGL(k_tree, dim3(256), dim3(512), 0, stream, leaves, PBH, PBL,
                     ws, out);
}